// Round 5
// baseline (731.156 us; speedup 1.0000x reference)
//
#include <hip/hip_runtime.h>

#define BLOCK 256
#define NPB 64          // nodes per block (one per lane; 4 waves split columns)
#define NF 8            // node features
#define NE 32           // embed dim
#define NI 40           // F + E
#define NH 64           // hidden
#define SA_W 41         // input row stride, f32 (40+1; odd -> lane=node access 2-way max)
#define SB_W 66         // hidden row stride, f16 (66*2B=132B; dword stride 33 -> conflict-free)

typedef float fvec16 __attribute__((ext_vector_type(16)));
typedef float fvec8  __attribute__((ext_vector_type(8)));
typedef _Float16 h2v __attribute__((ext_vector_type(2)));

// Pre-pass: per main-kernel block, binary-search the segment containing its first node.
__global__ void seg_starts(const int* __restrict__ ptr, int* __restrict__ blockseg,
                           int nb, int n, int m)
{
    int b = blockIdx.x * blockDim.x + threadIdx.x;
    if (b >= nb) return;
    long long n0 = (long long)b * NPB;
    int node0 = (int)(n0 < n ? n0 : (long long)(n - 1));
    int lo = 0, hi = m;
    while (hi - lo > 1) {
        int mid = (lo + hi) >> 1;
        if (ptr[mid] <= node0) lo = mid; else hi = mid;
    }
    blockseg[b] = lo;
}

template<bool PRESEG>
__global__ __launch_bounds__(BLOCK, 8) void dag_mlp_seg(
    const float* __restrict__ x, const float* __restrict__ h_node,
    const float* __restrict__ W1, const float* __restrict__ b1,
    const float* __restrict__ W2, const float* __restrict__ b2,
    const float* __restrict__ W3, const float* __restrict__ b3,
    const int* __restrict__ ptr, float* __restrict__ out,
    const int* __restrict__ blockseg, int n, int m)
{
    // sA: input rows [x(8)|h_node(32)] f32, 64 x 41 x 4B = 10.25 KB
    // sB: hidden rows (H1, then H2 after a barrier) f16, 64 x 66 x 2B = 8.25 KB
    // total 18,944 B -> 8 blocks/CU (8 x 18,944 = 151,552 <= 163,840) = 32 waves/CU
    __shared__ float    sA[NPB * SA_W];
    __shared__ _Float16 sB[NPB * SB_W];

    const int tid = threadIdx.x;
    const int nd  = tid & 63;                                   // node-in-block = lane
    // wave id; readfirstlane makes it provably uniform so weight-row loads
    // become s_load_dwordx16 (SGPRs), not per-lane vector loads.
    const int g   = __builtin_amdgcn_readfirstlane(tid >> 6);   // 0..3
    const long long node0 = (long long)blockIdx.x * NPB;

    // ---- stage inputs into sA rows: [x(8) | h_node(32)] ----
    {
        // x: 64 nodes * 8 floats = 128 float4
        const long long x4max  = ((long long)n * NF) / 4 - 1;
        const long long h4max  = ((long long)n * NE) / 4 - 1;
        if (tid < 128) {
            long long gi = node0 * (NF / 4) + tid;
            if (gi > x4max) gi = x4max;          // tail clamp (outputs guarded later)
            float4 v = reinterpret_cast<const float4*>(x)[gi];
            const int nd2 = tid >> 1, c = (tid & 1) * 4;
            float* p = &sA[nd2 * SA_W + c];
            p[0] = v.x; p[1] = v.y; p[2] = v.z; p[3] = v.w;
        }
        // h_node: 64 nodes * 32 floats = 512 float4, 2 per thread
#pragma unroll
        for (int r = 0; r < 2; ++r) {
            const int j = tid + r * BLOCK;       // 0..511
            long long gi = node0 * (NE / 4) + j;
            if (gi > h4max) gi = h4max;
            float4 v = reinterpret_cast<const float4*>(h_node)[gi];
            const int nd2 = j >> 3, c = (j & 7) * 4;
            float* p = &sA[nd2 * SA_W + NF + c];
            p[0] = v.x; p[1] = v.y; p[2] = v.z; p[3] = v.w;
        }
    }
    __syncthreads();

    // ---- layer 1: [40] -> [64], this wave computes cols g*16..g*16+15 ----
    float acc[16];
    {
        fvec16 bv = *reinterpret_cast<const fvec16*>(b1 + g * 16);
#pragma unroll
        for (int c = 0; c < 16; ++c) acc[c] = bv[c];
        const float* inRow = &sA[nd * SA_W];
#pragma unroll 8
        for (int k = 0; k < NI; ++k) {
            const float s = inRow[k];                                   // ds_read_b32
            fvec16 w = *reinterpret_cast<const fvec16*>(W1 + k * NH + g * 16); // s_load x16
#pragma unroll
            for (int c = 0; c < 16; ++c) acc[c] = fmaf(s, w[c], acc[c]);
        }
        // relu + cvt to f16, packed pair writes (ds_write_b32), conflict-free
        _Float16* o = &sB[nd * SB_W + g * 16];
#pragma unroll
        for (int i = 0; i < 8; ++i) {
            h2v p = { (_Float16)fmaxf(acc[2*i],   0.f),
                      (_Float16)fmaxf(acc[2*i+1], 0.f) };
            *reinterpret_cast<h2v*>(o + 2*i) = p;
        }
    }
    __syncthreads();

    // ---- layer 2: [64] -> [64], reads sB (H1 f16); H2 overwrites sB after a barrier ----
    {
        fvec16 bv = *reinterpret_cast<const fvec16*>(b2 + g * 16);
#pragma unroll
        for (int c = 0; c < 16; ++c) acc[c] = bv[c];
        const _Float16* inRow = &sB[nd * SB_W];
#pragma unroll 8
        for (int k = 0; k < NH; ++k) {
            const float s = (float)inRow[k];                   // ds_read_u16 + cvt
            fvec16 w = *reinterpret_cast<const fvec16*>(W2 + k * NH + g * 16);
#pragma unroll
            for (int c = 0; c < 16; ++c) acc[c] = fmaf(s, w[c], acc[c]);
        }
    }
    __syncthreads();       // all H1 reads complete before anyone overwrites sB
    {
        _Float16* o = &sB[nd * SB_W + g * 16];
#pragma unroll
        for (int i = 0; i < 8; ++i) {
            h2v p = { (_Float16)fmaxf(acc[2*i],   0.f),
                      (_Float16)fmaxf(acc[2*i+1], 0.f) };
            *reinterpret_cast<h2v*>(o + 2*i) = p;
        }
    }
    __syncthreads();

    // ---- layer 3: [64] -> [32], this wave computes cols g*8..g*8+7 ----
    float ov[8];
    {
        fvec8 bv = *reinterpret_cast<const fvec8*>(b3 + g * 8);
#pragma unroll
        for (int c = 0; c < 8; ++c) ov[c] = bv[c];
        const _Float16* inRow = &sB[nd * SB_W];
#pragma unroll 8
        for (int k = 0; k < NH; ++k) {
            const float s = (float)inRow[k];
            fvec8 w = *reinterpret_cast<const fvec8*>(W3 + k * NE + g * 8);
#pragma unroll
            for (int c = 0; c < 8; ++c) ov[c] = fmaf(s, w[c], ov[c]);
        }
    }

    // ---- segment id ----
    const long long node = node0 + nd;
    const bool valid = node < n;
    const int nodeC = (int)(valid ? node : (long long)(n - 1));
    int seg;
    if constexpr (PRESEG) {
        seg = blockseg[blockIdx.x];          // 1 load (L2-hot)
    } else {
        // wave-uniform binary search on the block's first node
        const int node0C = (int)(node0 < n ? node0 : (long long)(n - 1));
        int lo = 0, hi = m;
        while (hi - lo > 1) {
            int mid = (lo + hi) >> 1;
            if (ptr[mid] <= node0C) lo = mid; else hi = mid;
        }
        seg = lo;
    }
    // advance to largest seg with ptr[seg] <= nodeC (avg ~0.64 trips/block; L1-hot)
    while (seg + 1 < m && ptr[seg + 1] <= nodeC) ++seg;

    // ---- wave-level segmented suffix reduction; lanes = consecutive nodes ----
    const int lane = nd;
    const int segUp = __shfl_up(seg, 1);
    const bool head = (lane == 0) || (segUp != seg);

    bool take[6];
#pragma unroll
    for (int i = 0; i < 6; ++i) {
        const int d = 1 << i;
        const int s2 = __shfl_down(seg, d);
        take[i] = (lane + d < 64) && (s2 == seg);
    }

#pragma unroll
    for (int j = 0; j < 8; ++j) {
        float v = valid ? ov[j] : 0.f;
#pragma unroll
        for (int i = 0; i < 6; ++i) {
            const float w = __shfl_down(v, 1 << i);
            if (take[i]) v += w;
        }
        if (head && valid) {
            atomicAdd(&out[(size_t)seg * NE + g * 8 + j], v);
        }
    }
}

extern "C" void kernel_launch(void* const* d_in, const int* in_sizes, int n_in,
                              void* d_out, int out_size, void* d_ws, size_t ws_size,
                              hipStream_t stream) {
    const float* x      = (const float*)d_in[0];
    const float* h_node = (const float*)d_in[1];
    const float* W1     = (const float*)d_in[2];
    const float* b1     = (const float*)d_in[3];
    const float* W2     = (const float*)d_in[4];
    const float* b2     = (const float*)d_in[5];
    const float* W3     = (const float*)d_in[6];
    const float* b3     = (const float*)d_in[7];
    const int*   ptr    = (const int*)d_in[8];
    float* out = (float*)d_out;

    const int n = in_sizes[0] / NF;   // 2,000,000 nodes
    const int m = out_size / NE;      // 20,000 segments

    // out is accumulated with atomics; harness poisons it with 0xAA.
    hipMemsetAsync(d_out, 0, (size_t)out_size * sizeof(float), stream);

    const int nb = (n + NPB - 1) / NPB;
    const bool preseg = (d_ws != nullptr) && (ws_size >= (size_t)nb * sizeof(int));

    if (preseg) {
        int* blockseg = (int*)d_ws;
        seg_starts<<<(nb + 255) / 256, 256, 0, stream>>>(ptr, blockseg, nb, n, m);
        dag_mlp_seg<true><<<nb, BLOCK, 0, stream>>>(x, h_node, W1, b1, W2, b2, W3, b3,
                                                    ptr, out, blockseg, n, m);
    } else {
        dag_mlp_seg<false><<<nb, BLOCK, 0, stream>>>(x, h_node, W1, b1, W2, b2, W3, b3,
                                                     ptr, out, nullptr, n, m);
    }
}